// Round 1
// baseline (1004.622 us; speedup 1.0000x reference)
//
#include <hip/hip_runtime.h>

// E2V layer: out[n, o] = relu( sum_k concat(he[i0[n]], he[i1[n]], node[n])[k] * W[o][k] + b[o] )
// N_INC = 2,000,000 incidences, K = 192, D_OUT = 64.
// Strategy: bf16 MFMA (16x16x32), one wave per 16-incidence tile, grid-stride.
// B (W^T) fragments + bias cached in registers across tiles.

typedef __bf16 bf16x8 __attribute__((ext_vector_type(8)));
typedef float  f32x4  __attribute__((ext_vector_type(4)));

static __device__ __forceinline__ bf16x8 cvt8(f32x4 a, f32x4 b) {
  bf16x8 r;
  r[0] = (__bf16)a[0]; r[1] = (__bf16)a[1]; r[2] = (__bf16)a[2]; r[3] = (__bf16)a[3];
  r[4] = (__bf16)b[0]; r[5] = (__bf16)b[1]; r[6] = (__bf16)b[2]; r[7] = (__bf16)b[3];
  return r;
}

static __device__ __forceinline__ bf16x8 load_frag(const float* __restrict__ p) {
  f32x4 a = *(const f32x4*)p;
  f32x4 b = *(const f32x4*)(p + 4);
  return cvt8(a, b);
}

#define N_INC    2000000
#define N_TILES  (N_INC / 16)   // 125000

__global__ __launch_bounds__(256, 2) void e2v_mfma(
    const float* __restrict__ hyperedge,   // [100000, 64]
    const float* __restrict__ hyper_node,  // [N_INC, 64]
    const int*   __restrict__ aff,         // [2, N_INC] int32
    const float* __restrict__ W,           // [64, 192] row-major (torch [out,in])
    const float* __restrict__ bias,        // [64]
    float*       __restrict__ out)         // [N_INC, 64]
{
  const int lane = threadIdx.x & 63;
  const int wid  = (blockIdx.x * blockDim.x + threadIdx.x) >> 6;
  const int nw   = (gridDim.x * blockDim.x) >> 6;
  const int m    = lane & 15;     // A row / B col within tile
  const int quad = lane >> 4;     // k sub-offset selector
  const int koff = quad * 8;      // lane's 8 consecutive k within a 32-k frag

  // B fragments: Bf[t][f] holds B[k][n] = W[t*16+m][f*32 + koff + j], j=0..7
  bf16x8 Bf[4][6];
  #pragma unroll
  for (int t = 0; t < 4; ++t) {
    const float* wr = W + (t * 16 + m) * 192 + koff;
    #pragma unroll
    for (int f = 0; f < 6; ++f)
      Bf[t][f] = load_frag(wr + f * 32);
  }
  float bv[4];
  #pragma unroll
  for (int t = 0; t < 4; ++t) bv[t] = bias[t * 16 + m];

  const int* __restrict__ aff0 = aff;
  const int* __restrict__ aff1 = aff + N_INC;

  for (int tile = wid; tile < N_TILES; tile += nw) {
    const int n_base = tile * 16;
    const int i0 = aff0[n_base + m];
    const int i1 = aff1[n_base + m];
    const float* e0 = hyperedge  + (long)i0 * 64 + koff;
    const float* e1 = hyperedge  + (long)i1 * 64 + koff;
    const float* nd = hyper_node + (long)(n_base + m) * 64 + koff;

    // A fragments: A[m][k] = concat(edge_i, edge_j, node)[n_base+m][k]
    bf16x8 A[6];
    A[0] = load_frag(e0);        // k   0..31
    A[1] = load_frag(e0 + 32);   // k  32..63
    A[2] = load_frag(e1);        // k  64..95
    A[3] = load_frag(e1 + 32);   // k  96..127
    A[4] = load_frag(nd);        // k 128..159
    A[5] = load_frag(nd + 32);   // k 160..191

    f32x4 acc[4] = { {0.f,0.f,0.f,0.f}, {0.f,0.f,0.f,0.f},
                     {0.f,0.f,0.f,0.f}, {0.f,0.f,0.f,0.f} };
    #pragma unroll
    for (int f = 0; f < 6; ++f) {
      #pragma unroll
      for (int t = 0; t < 4; ++t)
        acc[t] = __builtin_amdgcn_mfma_f32_16x16x32_bf16(A[f], Bf[t][f], acc[t], 0, 0, 0);
    }

    // D layout: col = lane&15 -> output channel (within n-tile t), row = quad*4+r -> incidence
    #pragma unroll
    for (int t = 0; t < 4; ++t) {
      const int o = t * 16 + m;
      #pragma unroll
      for (int r = 0; r < 4; ++r) {
        const int inc = n_base + quad * 4 + r;
        float v = acc[t][r] + bv[t];
        out[(long)inc * 64 + o] = v > 0.f ? v : 0.f;
      }
    }
  }
}

extern "C" void kernel_launch(void* const* d_in, const int* in_sizes, int n_in,
                              void* d_out, int out_size, void* d_ws, size_t ws_size,
                              hipStream_t stream) {
  const float* hyperedge  = (const float*)d_in[0];
  const float* hyper_node = (const float*)d_in[1];
  const int*   aff        = (const int*)d_in[2];
  const float* W          = (const float*)d_in[3];
  const float* bias       = (const float*)d_in[4];
  float* out = (float*)d_out;

  dim3 grid(4096), block(256);   // 16384 waves, grid-stride over 125000 tiles
  hipLaunchKernelGGL(e2v_mfma, grid, block, 0, stream,
                     hyperedge, hyper_node, aff, W, bias, out);
}